// Round 3
// baseline (630.983 us; speedup 1.0000x reference)
//
#include <hip/hip_runtime.h>
#include <hip/hip_bf16.h>

// Hopfield sparsemax attention, MI355X gfx950.
// B=1, L=S=2048, D_MODEL=1024, H=16, DK=64.
//
// Input dtype (bf16 vs fp32) is detected AT RUNTIME on-device: reading fp32
// data as bf16 yields inf/NaN decodes from mantissa halves; genuine bf16
// N(0,1) data never exceeds ~6. Flag lives in ws[0]; all GEMMs branch
// (uniformly) on it for global-input loads, bias loads, and the final store.
//
// Pipeline (all on `stream`, graph-capture safe). Intermediates bf16 in ws:
//   0. detect dtype -> flag
//   1. Kb = bf16(keys @ Wk + bk)        [2048,1024]
//   2. Qb = bf16(queries @ Wq + bq)     [2048,1024]
//   3. Vb = bf16(Kb @ Wv + bv)          [2048,1024]   (reference quirk: V from key-projection)
//   4. Sc = (Qb_h @ Kb_h^T) / 8         fp32 chunk [hn, rn, S]
//   5. sparsemax rows (Michelot iteration, no sort), in place
//   6. Ob[h][l][d] = bf16(Sc_h @ Vb_h)  [H,2048,64] contiguous == reference's
//      transpose(2,1).view(L,-1) scramble viewed as [2048,1024]
//   7. out = Ob @ Wo + bo -> d_out (dtype per flag)

typedef __attribute__((ext_vector_type(8))) short short8;
typedef __attribute__((ext_vector_type(4))) float floatx4;

#define SRC_BF16 0
#define SRC_F32  1
#define SRC_RT   2

__device__ __forceinline__ short f2bf(float f) {
    __hip_bfloat16 h = __float2bfloat16(f);
    return *reinterpret_cast<const short*>(&h);
}

// Detect input dtype: decode first n shorts of q as bf16; fp32-read-as-bf16
// almost surely produces |x|>1e10 / inf / NaN. One 64-thread block.
__global__ void detect_k(const short* __restrict__ q, int n, int* __restrict__ flag)
{
    const int tid = threadIdx.x;
    int bad = 0;
    for (int i = tid; i < n; i += 64) {
        unsigned u = ((unsigned)(unsigned short)q[i]) << 16;
        float f = __uint_as_float(u);
        if (!(fabsf(f) < 1e10f)) bad = 1;   // catches huge/inf/NaN
    }
    unsigned long long m = __ballot(bad != 0);
    if (tid == 0) *flag = (m != 0ULL) ? 1 : 0;
}

// Generic MFMA bf16 GEMM: C = alpha * A @ B (+ bias), A:[M,K], B:[K,N] (or Bt:[N,K]),
// tile 64x64, BK=32, 256 threads = 4 waves in 2x2, each wave 2x2 mfma_f32_16x16x32_bf16.
// M,N multiples of 64; K multiple of 32. ASRC/BSRC/OSRC: 0=bf16, 1=f32, 2=runtime(flag).
template<int ASRC, int BSRC, bool B_TRANS, int OSRC, bool HAS_BIAS>
__global__ __launch_bounds__(256)
void gemm_k(const void* __restrict__ Ap, long lda, long sA,
            const void* __restrict__ Bp, long ldb, long sB,
            const void* __restrict__ bias,
            void* __restrict__ Cp, long ldc, long sC,
            int M, int N, int K, float alpha,
            const int* __restrict__ dflag)
{
    __shared__ __align__(16) short As[64][40];   // [m][k], +8 pad
    __shared__ __align__(16) short Bs[64][40];   // [n][k], +8 pad

    int rtf = 0;
    if (ASRC == SRC_RT || BSRC == SRC_RT || OSRC == SRC_RT || HAS_BIAS)
        rtf = *dflag;   // uniform scalar load + branch

    const int tid  = threadIdx.x;
    const int bN   = blockIdx.x, bM = blockIdx.y, bz = blockIdx.z;
    const int lane = tid & 63, wave = tid >> 6;
    const int wm   = (wave >> 1) * 32;
    const int wn   = (wave & 1) * 32;
    const int quad = lane >> 4, r16 = lane & 15;

    floatx4 acc[2][2];
    #pragma unroll
    for (int i = 0; i < 2; ++i)
        #pragma unroll
        for (int j = 0; j < 2; ++j)
            acc[i][j] = (floatx4){0.f, 0.f, 0.f, 0.f};

    const int ar = tid >> 2, ac = (tid & 3) * 8;   // 64 rows x 32 cols staging
    const int bk_ = tid >> 3, bn_ = (tid & 7) * 8; // 32 rows x 64 cols staging

    const size_t aOff = (size_t)bz * (size_t)sA;
    const size_t bOff = (size_t)bz * (size_t)sB;

    const bool af32 = (ASRC == SRC_F32) || (ASRC == SRC_RT && rtf);
    const bool bf32 = (BSRC == SRC_F32) || (BSRC == SRC_RT && rtf);

    for (int k0 = 0; k0 < K; k0 += 32) {
        // ---- stage A tile: As[r][c] = A[bM*64 + r][k0 + c] ----
        {
            const size_t idx = aOff + (size_t)(bM * 64 + ar) * (size_t)lda + (size_t)(k0 + ac);
            short8 av;
            if (af32) {
                const float4* p = (const float4*)((const float*)Ap + idx);
                float4 f0 = p[0], f1 = p[1];
                av[0] = f2bf(f0.x); av[1] = f2bf(f0.y); av[2] = f2bf(f0.z); av[3] = f2bf(f0.w);
                av[4] = f2bf(f1.x); av[5] = f2bf(f1.y); av[6] = f2bf(f1.z); av[7] = f2bf(f1.w);
            } else {
                av = *(const short8*)((const short*)Ap + idx);
            }
            *(short8*)&As[ar][ac] = av;
        }
        // ---- stage B tile into Bs[n][k] ----
        if (B_TRANS) {
            // B stored [N,K]: straight copy
            const size_t idx = bOff + (size_t)(bN * 64 + ar) * (size_t)ldb + (size_t)(k0 + ac);
            short8 bvv;
            if (bf32) {
                const float4* p = (const float4*)((const float*)Bp + idx);
                float4 f0 = p[0], f1 = p[1];
                bvv[0] = f2bf(f0.x); bvv[1] = f2bf(f0.y); bvv[2] = f2bf(f0.z); bvv[3] = f2bf(f0.w);
                bvv[4] = f2bf(f1.x); bvv[5] = f2bf(f1.y); bvv[6] = f2bf(f1.z); bvv[7] = f2bf(f1.w);
            } else {
                bvv = *(const short8*)((const short*)Bp + idx);
            }
            *(short8*)&Bs[ar][ac] = bvv;
        } else {
            // B stored [K,N]: read coalesced rows, write transposed
            const size_t idx = bOff + (size_t)(k0 + bk_) * (size_t)ldb + (size_t)(bN * 64 + bn_);
            short tmp[8];
            if (bf32) {
                const float4* p = (const float4*)((const float*)Bp + idx);
                float4 f0 = p[0], f1 = p[1];
                tmp[0] = f2bf(f0.x); tmp[1] = f2bf(f0.y); tmp[2] = f2bf(f0.z); tmp[3] = f2bf(f0.w);
                tmp[4] = f2bf(f1.x); tmp[5] = f2bf(f1.y); tmp[6] = f2bf(f1.z); tmp[7] = f2bf(f1.w);
            } else {
                short8 s = *(const short8*)((const short*)Bp + idx);
                #pragma unroll
                for (int j = 0; j < 8; ++j) tmp[j] = s[j];
            }
            #pragma unroll
            for (int j = 0; j < 8; ++j) Bs[bn_ + j][bk_] = tmp[j];
        }
        __syncthreads();

        // fragments: A[m=lane&15][k=quad*8+j], B[k=quad*8+j][n=lane&15] (from Bs[n][k])
        short8 a0 = *(const short8*)&As[wm + r16][quad * 8];
        short8 a1 = *(const short8*)&As[wm + 16 + r16][quad * 8];
        short8 b0 = *(const short8*)&Bs[wn + r16][quad * 8];
        short8 b1 = *(const short8*)&Bs[wn + 16 + r16][quad * 8];

        acc[0][0] = __builtin_amdgcn_mfma_f32_16x16x32_bf16(a0, b0, acc[0][0], 0, 0, 0);
        acc[0][1] = __builtin_amdgcn_mfma_f32_16x16x32_bf16(a0, b1, acc[0][1], 0, 0, 0);
        acc[1][0] = __builtin_amdgcn_mfma_f32_16x16x32_bf16(a1, b0, acc[1][0], 0, 0, 0);
        acc[1][1] = __builtin_amdgcn_mfma_f32_16x16x32_bf16(a1, b1, acc[1][1], 0, 0, 0);
        __syncthreads();
    }

    // epilogue: C/D layout col=lane&15, row=quad*4+reg
    const size_t cOff = (size_t)bz * (size_t)sC;
    const bool of32 = (OSRC == SRC_F32) || (OSRC == SRC_RT && rtf);
    #pragma unroll
    for (int i = 0; i < 2; ++i) {
        #pragma unroll
        for (int j = 0; j < 2; ++j) {
            const int gc = bN * 64 + wn + j * 16 + r16;
            float bb = 0.0f;
            if (HAS_BIAS)
                bb = rtf ? ((const float*)bias)[gc]
                         : __bfloat162float(((const __hip_bfloat16*)bias)[gc]);
            #pragma unroll
            for (int rg = 0; rg < 4; ++rg) {
                const int gr = bM * 64 + wm + i * 16 + quad * 4 + rg;
                float v = acc[i][j][rg] * alpha + bb;
                if (of32)
                    ((float*)Cp)[cOff + (size_t)gr * (size_t)ldc + gc] = v;
                else
                    ((__hip_bfloat16*)Cp)[cOff + (size_t)gr * (size_t)ldc + gc] = __float2bfloat16(v);
            }
        }
    }
}

// Sparsemax over rows of length S=2048, in place, fp32. One 256-thread block per row.
// Michelot: tau <- (sum_{z>tau} z - 1)/|{z>tau}|; active set shrinks monotonically;
// fixed point is the exact sparsemax threshold. Then out = max(z - tau, 0).
__global__ __launch_bounds__(256)
void sparsemax_k(float* __restrict__ sc, int S)
{
    float* z = sc + (size_t)blockIdx.x * (size_t)S;
    const int tid = threadIdx.x;
    const int lane = tid & 63, wv = tid >> 6;

    float v[8];
    #pragma unroll
    for (int j = 0; j < 8; ++j) v[j] = z[tid + j * 256];

    __shared__ float red_s[4], red_c[4];

    float ls = 0.f;
    #pragma unroll
    for (int j = 0; j < 8; ++j) ls += v[j];
    #pragma unroll
    for (int off = 32; off > 0; off >>= 1) ls += __shfl_down(ls, off, 64);
    if (lane == 0) red_s[wv] = ls;
    __syncthreads();
    float tau = (red_s[0] + red_s[1] + red_s[2] + red_s[3] - 1.0f) / (float)S;
    float prevCnt = (float)S;

    for (int it = 0; it < 64; ++it) {
        __syncthreads();
        float s = 0.f, c = 0.f;
        #pragma unroll
        for (int j = 0; j < 8; ++j)
            if (v[j] > tau) { s += v[j]; c += 1.f; }
        #pragma unroll
        for (int off = 32; off > 0; off >>= 1) {
            s += __shfl_down(s, off, 64);
            c += __shfl_down(c, off, 64);
        }
        if (lane == 0) { red_s[wv] = s; red_c[wv] = c; }
        __syncthreads();
        float S_ = red_s[0] + red_s[1] + red_s[2] + red_s[3];
        float C_ = red_c[0] + red_c[1] + red_c[2] + red_c[3];
        if (C_ == prevCnt) break;   // active set stable -> converged (uniform across block)
        prevCnt = C_;
        tau = (S_ - 1.0f) / C_;
    }

    #pragma unroll
    for (int j = 0; j < 8; ++j) z[tid + j * 256] = fmaxf(v[j] - tau, 0.f);
}

extern "C" void kernel_launch(void* const* d_in, const int* in_sizes, int n_in,
                              void* d_out, int out_size, void* d_ws, size_t ws_size,
                              hipStream_t stream)
{
    (void)in_sizes; (void)n_in; (void)out_size;

    const void* queries = d_in[0];
    const void* keys    = d_in[1];
    // d_in[2] ("values") is unused by the reference.
    const void* Wq = d_in[3];
    const void* bq = d_in[4];
    const void* Wk = d_in[5];
    const void* bk = d_in[6];
    const void* Wv = d_in[7];
    const void* bv = d_in[8];
    const void* Wo = d_in[9];
    const void* bo = d_in[10];

    const int L = 2048, S = 2048, DM = 1024, H = 16, DKd = 64;
    const size_t LD = (size_t)L * DM;   // 2M elements

    int*   flag = (int*)d_ws;
    short* Qb = (short*)((char*)d_ws + 256);   // [L, 1024] bf16
    short* Kb = Qb + LD;                       // [S, 1024] bf16
    short* Vb = Kb + LD;                       // [S, 1024] bf16
    short* Ob = Vb + LD;                       // [H, L, 64] bf16 contiguous
    float* Sc = (float*)(Ob + LD);             // fp32 score chunk

    const size_t fixedBytes = 256 + 4 * LD * sizeof(short);  // ~16 MB
    size_t remain = ws_size > fixedBytes ? ws_size - fixedBytes : 0;

    // Chunking: prefer whole heads batched via grid.z; else row-chunk one head.
    const size_t headScBytes = (size_t)L * S * sizeof(float);  // 16 MB
    int hc = (int)(remain / headScBytes);
    int Rc;
    if (hc >= 1) { if (hc > H) hc = H; Rc = L; }
    else {
        hc = 1;
        long rows = (long)(remain / ((size_t)S * sizeof(float)));
        rows &= ~63L;
        if (rows < 64) rows = 64;      // ws floor ~16.5 MB
        if (rows > L) rows = L;
        Rc = (int)rows;
    }

    dim3 blk(256);

    // 0) dtype detection
    detect_k<<<dim3(1), dim3(64), 0, stream>>>((const short*)queries, 4096, flag);

    // 1) Kb = keys @ Wk + bk
    gemm_k<SRC_RT, SRC_RT, false, SRC_BF16, true><<<dim3(DM / 64, L / 64, 1), blk, 0, stream>>>(
        keys, DM, 0, Wk, DM, 0, bk, Kb, DM, 0, L, DM, DM, 1.0f, flag);
    // 2) Qb = queries @ Wq + bq
    gemm_k<SRC_RT, SRC_RT, false, SRC_BF16, true><<<dim3(DM / 64, L / 64, 1), blk, 0, stream>>>(
        queries, DM, 0, Wq, DM, 0, bq, Qb, DM, 0, L, DM, DM, 1.0f, flag);
    // 3) Vb = Kb @ Wv + bv
    gemm_k<SRC_BF16, SRC_RT, false, SRC_BF16, true><<<dim3(DM / 64, L / 64, 1), blk, 0, stream>>>(
        Kb, DM, 0, Wv, DM, 0, bv, Vb, DM, 0, S, DM, DM, 1.0f, flag);

    for (int h0 = 0; h0 < H; h0 += hc) {
        const int hn = (H - h0) < hc ? (H - h0) : hc;
        for (int r0 = 0; r0 < L; r0 += Rc) {
            const int rn = (L - r0) < Rc ? (L - r0) : Rc;
            // 4) Sc[z] = (Qb_h[r0:r0+rn] @ Kb_h^T) / 8
            gemm_k<SRC_BF16, SRC_BF16, true, SRC_F32, false><<<dim3(S / 64, rn / 64, hn), blk, 0, stream>>>(
                Qb + (size_t)r0 * DM + (size_t)h0 * DKd, DM, DKd,
                Kb + (size_t)h0 * DKd, DM, DKd,
                nullptr,
                Sc, S, (long)rn * S,
                rn, S, DKd, 0.125f, flag);
            // 5) sparsemax in place
            sparsemax_k<<<dim3(hn * rn), blk, 0, stream>>>(Sc, S);
            // 6) Ob[h][r0:r0+rn] = Sc_h @ Vb_h   (bf16 out, [h][l][d] contiguous)
            gemm_k<SRC_F32, SRC_BF16, false, SRC_BF16, false><<<dim3(DKd / 64, rn / 64, hn), blk, 0, stream>>>(
                Sc, S, (long)rn * S,
                Vb + (size_t)h0 * DKd, DM, DKd,
                nullptr,
                Ob + ((size_t)h0 * L + r0) * DKd, DKd, (long)L * DKd,
                rn, DKd, S, 1.0f, flag);
        }
    }

    // 7) out = Ob(viewed [2048,1024]) @ Wo + bo -> d_out (dtype per flag)
    gemm_k<SRC_BF16, SRC_RT, false, SRC_RT, true><<<dim3(DM / 64, L / 64, 1), blk, 0, stream>>>(
        Ob, DM, 0, Wo, DM, 0, bo, d_out, DM, 0, L, DM, DM, 1.0f, flag);
}

// Round 4
// 503.633 us; speedup vs baseline: 1.2529x; 1.2529x over previous
//
#include <hip/hip_runtime.h>
#include <hip/hip_bf16.h>

// Hopfield sparsemax attention, MI355X gfx950.
// B=1, L=S=2048, D_MODEL=1024, H=16, DK=64. Inputs fp32 (runtime-detected), output per flag.
//
// Pipeline (all on `stream`, graph-capture safe). Intermediates bf16 in ws:
//   0. detect dtype -> flag
//   1. Kb = bf16(keys @ Wk + bk)        [2048,1024]
//   2. Qb = bf16(queries @ Wq + bq)     [2048,1024]
//   3. Vb = bf16(Kb @ Wv + bv)          [2048,1024]   (reference quirk: V from key-projection)
//   4. Sc = (Qb_h @ Kb_h^T) / 8         fp32 [hn, rn, S]  (128x128-tile MFMA GEMM)
//   5. sparsemax rows: max-pruned Michelot (support subset of {z >= max-1}), wave-0 solve,
//      writes P as bf16 IN PLACE over the fp32 row (row r -> bf16[2048] at same base)
//   6. Ob[h][l][d] = bf16(P_h @ Vb_h)   [H,2048,64] contiguous == reference's
//      transpose(2,1).view(L,-1) scramble viewed as [2048,1024]
//   7. out = Ob @ Wo + bo -> d_out (dtype per flag)

typedef __attribute__((ext_vector_type(8))) short short8;
typedef __attribute__((ext_vector_type(4))) float floatx4;

#define SRC_BF16 0
#define SRC_F32  1
#define SRC_RT   2

__device__ __forceinline__ short f2bf(float f) {
    __hip_bfloat16 h = __float2bfloat16(f);
    return *reinterpret_cast<const short*>(&h);
}

// Detect input dtype: decode first n shorts of q as bf16; fp32-read-as-bf16
// almost surely produces |x|>1e10 / inf / NaN. One 64-thread block.
__global__ void detect_k(const short* __restrict__ q, int n, int* __restrict__ flag)
{
    const int tid = threadIdx.x;
    int bad = 0;
    for (int i = tid; i < n; i += 64) {
        unsigned u = ((unsigned)(unsigned short)q[i]) << 16;
        float f = __uint_as_float(u);
        if (!(fabsf(f) < 1e10f)) bad = 1;
    }
    unsigned long long m = __ballot(bad != 0);
    if (tid == 0) *flag = (m != 0ULL) ? 1 : 0;
}

// ---------------- generic 64x64-tile GEMM (projections / AV / final) ----------------
// C = alpha * A @ B (+ bias). A:[M,K], B:[K,N] (or Bt:[N,K]). BK=32, 4 waves 2x2,
// each wave 2x2 mfma_f32_16x16x32_bf16. ASRC/BSRC/OSRC: 0=bf16, 1=f32, 2=runtime(flag).
template<int ASRC, int BSRC, bool B_TRANS, int OSRC, bool HAS_BIAS>
__global__ __launch_bounds__(256)
void gemm_k(const void* __restrict__ Ap, long lda, long sA,
            const void* __restrict__ Bp, long ldb, long sB,
            const void* __restrict__ bias,
            void* __restrict__ Cp, long ldc, long sC,
            int M, int N, int K, float alpha,
            const int* __restrict__ dflag)
{
    __shared__ __align__(16) short As[64][40];
    __shared__ __align__(16) short Bs[64][40];

    int rtf = 0;
    if (ASRC == SRC_RT || BSRC == SRC_RT || OSRC == SRC_RT || HAS_BIAS)
        rtf = *dflag;

    const int tid  = threadIdx.x;
    const int bN   = blockIdx.x, bM = blockIdx.y, bz = blockIdx.z;
    const int lane = tid & 63, wave = tid >> 6;
    const int wm   = (wave >> 1) * 32;
    const int wn   = (wave & 1) * 32;
    const int quad = lane >> 4, r16 = lane & 15;

    floatx4 acc[2][2];
    #pragma unroll
    for (int i = 0; i < 2; ++i)
        #pragma unroll
        for (int j = 0; j < 2; ++j)
            acc[i][j] = (floatx4){0.f, 0.f, 0.f, 0.f};

    const int ar = tid >> 2, ac = (tid & 3) * 8;
    const int bk_ = tid >> 3, bn_ = (tid & 7) * 8;

    const size_t aOff = (size_t)bz * (size_t)sA;
    const size_t bOff = (size_t)bz * (size_t)sB;

    const bool af32 = (ASRC == SRC_F32) || (ASRC == SRC_RT && rtf);
    const bool bf32 = (BSRC == SRC_F32) || (BSRC == SRC_RT && rtf);

    for (int k0 = 0; k0 < K; k0 += 32) {
        {
            const size_t idx = aOff + (size_t)(bM * 64 + ar) * (size_t)lda + (size_t)(k0 + ac);
            short8 av;
            if (af32) {
                const float4* p = (const float4*)((const float*)Ap + idx);
                float4 f0 = p[0], f1 = p[1];
                av[0] = f2bf(f0.x); av[1] = f2bf(f0.y); av[2] = f2bf(f0.z); av[3] = f2bf(f0.w);
                av[4] = f2bf(f1.x); av[5] = f2bf(f1.y); av[6] = f2bf(f1.z); av[7] = f2bf(f1.w);
            } else {
                av = *(const short8*)((const short*)Ap + idx);
            }
            *(short8*)&As[ar][ac] = av;
        }
        if (B_TRANS) {
            const size_t idx = bOff + (size_t)(bN * 64 + ar) * (size_t)ldb + (size_t)(k0 + ac);
            short8 bvv;
            if (bf32) {
                const float4* p = (const float4*)((const float*)Bp + idx);
                float4 f0 = p[0], f1 = p[1];
                bvv[0] = f2bf(f0.x); bvv[1] = f2bf(f0.y); bvv[2] = f2bf(f0.z); bvv[3] = f2bf(f0.w);
                bvv[4] = f2bf(f1.x); bvv[5] = f2bf(f1.y); bvv[6] = f2bf(f1.z); bvv[7] = f2bf(f1.w);
            } else {
                bvv = *(const short8*)((const short*)Bp + idx);
            }
            *(short8*)&Bs[ar][ac] = bvv;
        } else {
            const size_t idx = bOff + (size_t)(k0 + bk_) * (size_t)ldb + (size_t)(bN * 64 + bn_);
            short tmp[8];
            if (bf32) {
                const float4* p = (const float4*)((const float*)Bp + idx);
                float4 f0 = p[0], f1 = p[1];
                tmp[0] = f2bf(f0.x); tmp[1] = f2bf(f0.y); tmp[2] = f2bf(f0.z); tmp[3] = f2bf(f0.w);
                tmp[4] = f2bf(f1.x); tmp[5] = f2bf(f1.y); tmp[6] = f2bf(f1.z); tmp[7] = f2bf(f1.w);
            } else {
                short8 s = *(const short8*)((const short*)Bp + idx);
                #pragma unroll
                for (int j = 0; j < 8; ++j) tmp[j] = s[j];
            }
            #pragma unroll
            for (int j = 0; j < 8; ++j) Bs[bn_ + j][bk_] = tmp[j];
        }
        __syncthreads();

        short8 a0 = *(const short8*)&As[wm + r16][quad * 8];
        short8 a1 = *(const short8*)&As[wm + 16 + r16][quad * 8];
        short8 b0 = *(const short8*)&Bs[wn + r16][quad * 8];
        short8 b1 = *(const short8*)&Bs[wn + 16 + r16][quad * 8];

        acc[0][0] = __builtin_amdgcn_mfma_f32_16x16x32_bf16(a0, b0, acc[0][0], 0, 0, 0);
        acc[0][1] = __builtin_amdgcn_mfma_f32_16x16x32_bf16(a0, b1, acc[0][1], 0, 0, 0);
        acc[1][0] = __builtin_amdgcn_mfma_f32_16x16x32_bf16(a1, b0, acc[1][0], 0, 0, 0);
        acc[1][1] = __builtin_amdgcn_mfma_f32_16x16x32_bf16(a1, b1, acc[1][1], 0, 0, 0);
        __syncthreads();
    }

    const size_t cOff = (size_t)bz * (size_t)sC;
    const bool of32 = (OSRC == SRC_F32) || (OSRC == SRC_RT && rtf);
    #pragma unroll
    for (int i = 0; i < 2; ++i) {
        #pragma unroll
        for (int j = 0; j < 2; ++j) {
            const int gc = bN * 64 + wn + j * 16 + r16;
            float bb = 0.0f;
            if (HAS_BIAS)
                bb = rtf ? ((const float*)bias)[gc]
                         : __bfloat162float(((const __hip_bfloat16*)bias)[gc]);
            #pragma unroll
            for (int rg = 0; rg < 4; ++rg) {
                const int gr = bM * 64 + wm + i * 16 + quad * 4 + rg;
                float v = acc[i][j][rg] * alpha + bb;
                if (of32)
                    ((float*)Cp)[cOff + (size_t)gr * (size_t)ldc + gc] = v;
                else
                    ((__hip_bfloat16*)Cp)[cOff + (size_t)gr * (size_t)ldc + gc] = __float2bfloat16(v);
            }
        }
    }
}

// ---------------- 128x128-tile GEMM for scores: bf16 A [M,K], bf16 Bt [N,K], fp32 C ----
// 4 waves 2x2, each wave 64x64 = 4x4 mfma_f32_16x16x32_bf16 subtiles. BK=32.
__global__ __launch_bounds__(256)
void gemm128_bt_k(const short* __restrict__ Ap, long lda, long sA,
                  const short* __restrict__ Bp, long ldb, long sB,
                  float* __restrict__ Cp, long ldc, long sC,
                  int K, float alpha)
{
    __shared__ __align__(16) short As[128][40];
    __shared__ __align__(16) short Bs[128][40];

    const int tid  = threadIdx.x;
    const int bN   = blockIdx.x, bM = blockIdx.y, bz = blockIdx.z;
    const int lane = tid & 63, wave = tid >> 6;
    const int wm   = (wave >> 1) * 64;
    const int wn   = (wave & 1) * 64;
    const int quad = lane >> 4, r16 = lane & 15;

    floatx4 acc[4][4];
    #pragma unroll
    for (int i = 0; i < 4; ++i)
        #pragma unroll
        for (int j = 0; j < 4; ++j)
            acc[i][j] = (floatx4){0.f, 0.f, 0.f, 0.f};

    const int ar = tid >> 2, ac = (tid & 3) * 8;
    const short* Abase = Ap + (size_t)bz * (size_t)sA;
    const short* Bbase = Bp + (size_t)bz * (size_t)sB;

    for (int k0 = 0; k0 < K; k0 += 32) {
        #pragma unroll
        for (int c = 0; c < 2; ++c) {
            const int row = c * 64 + ar;
            *(short8*)&As[row][ac] =
                *(const short8*)(Abase + (size_t)(bM * 128 + row) * (size_t)lda + (size_t)(k0 + ac));
            *(short8*)&Bs[row][ac] =
                *(const short8*)(Bbase + (size_t)(bN * 128 + row) * (size_t)ldb + (size_t)(k0 + ac));
        }
        __syncthreads();

        short8 af[4], bfr[4];
        #pragma unroll
        for (int i = 0; i < 4; ++i) af[i]  = *(const short8*)&As[wm + i * 16 + r16][quad * 8];
        #pragma unroll
        for (int j = 0; j < 4; ++j) bfr[j] = *(const short8*)&Bs[wn + j * 16 + r16][quad * 8];
        #pragma unroll
        for (int i = 0; i < 4; ++i)
            #pragma unroll
            for (int j = 0; j < 4; ++j)
                acc[i][j] = __builtin_amdgcn_mfma_f32_16x16x32_bf16(af[i], bfr[j], acc[i][j], 0, 0, 0);
        __syncthreads();
    }

    float* C = Cp + (size_t)bz * (size_t)sC;
    #pragma unroll
    for (int i = 0; i < 4; ++i)
        #pragma unroll
        for (int j = 0; j < 4; ++j) {
            const int gc = bN * 128 + wn + j * 16 + r16;
            #pragma unroll
            for (int rg = 0; rg < 4; ++rg) {
                const int gr = bM * 128 + wm + i * 16 + quad * 4 + rg;
                C[(size_t)gr * (size_t)ldc + gc] = acc[i][j][rg] * alpha;
            }
        }
}

// ---------------- sparsemax v2: max-pruned Michelot, bf16 in-place output ----------------
// One 256-thread block per row of S=2048. Support subset of {z >= M-1} (since the top
// probability M-tau <= 1 forces tau >= M-1). Candidates compacted into LDS (typ. < 50);
// wave 0 solves Michelot with shuffle-only reductions. Fallback to block-wide Michelot
// if candidates overflow (never for Gaussian scores). Output row written as bf16[2048]
// in place at the row's base (each thread writes only within the region it read).
__global__ __launch_bounds__(256)
void sparsemax_k(float* __restrict__ sc, int S)
{
    float* z = sc + (size_t)blockIdx.x * (size_t)S;
    const int tid = threadIdx.x;
    const int lane = tid & 63, wv = tid >> 6;

    float v[8];
    {
        const float4 f0 = *(const float4*)(z + tid * 8);
        const float4 f1 = *(const float4*)(z + tid * 8 + 4);
        v[0] = f0.x; v[1] = f0.y; v[2] = f0.z; v[3] = f0.w;
        v[4] = f1.x; v[5] = f1.y; v[6] = f1.z; v[7] = f1.w;
    }

    __shared__ float red_s[4], red_c[4], red_m[4];
    __shared__ float sh_tau;
    __shared__ int   sh_cnt;
    __shared__ float cand[512];

    // block max
    float m = v[0];
    #pragma unroll
    for (int j = 1; j < 8; ++j) m = fmaxf(m, v[j]);
    #pragma unroll
    for (int off = 32; off > 0; off >>= 1) m = fmaxf(m, __shfl_xor(m, off, 64));
    if (lane == 0) red_m[wv] = m;
    if (tid == 0) sh_cnt = 0;
    __syncthreads();
    const float M = fmaxf(fmaxf(red_m[0], red_m[1]), fmaxf(red_m[2], red_m[3]));
    const float thr = M - 1.0f;

    // candidate collection
    #pragma unroll
    for (int j = 0; j < 8; ++j) {
        if (v[j] >= thr) {
            int p = atomicAdd(&sh_cnt, 1);
            if (p < 512) cand[p] = v[j];
        }
    }
    __syncthreads();
    const int n = sh_cnt;

    if (n <= 512) {
        if (wv == 0) {
            float c0[8];
            #pragma unroll
            for (int i = 0; i < 8; ++i) {
                const int idx = lane + i * 64;
                c0[i] = (idx < n) ? cand[idx] : -3.0e38f;
            }
            float tau = -3.0e38f, prevc = -1.0f;
            for (int it = 0; it < 64; ++it) {
                float s = 0.f, c = 0.f;
                #pragma unroll
                for (int i = 0; i < 8; ++i)
                    if (c0[i] > tau) { s += c0[i]; c += 1.f; }
                #pragma unroll
                for (int off = 32; off > 0; off >>= 1) {
                    s += __shfl_xor(s, off, 64);
                    c += __shfl_xor(c, off, 64);
                }
                if (c == prevc) break;
                prevc = c;
                tau = (s - 1.0f) / c;
            }
            if (lane == 0) sh_tau = tau;
        }
    } else {
        // fallback: block-wide Michelot on full row (uniform branch; all threads here)
        float ls = 0.f;
        #pragma unroll
        for (int j = 0; j < 8; ++j) ls += v[j];
        #pragma unroll
        for (int off = 32; off > 0; off >>= 1) ls += __shfl_xor(ls, off, 64);
        if (lane == 0) red_s[wv] = ls;
        __syncthreads();
        float tau = (red_s[0] + red_s[1] + red_s[2] + red_s[3] - 1.0f) / (float)S;
        float prevc = (float)S;
        for (int it = 0; it < 64; ++it) {
            __syncthreads();
            float s = 0.f, c = 0.f;
            #pragma unroll
            for (int j = 0; j < 8; ++j)
                if (v[j] > tau) { s += v[j]; c += 1.f; }
            #pragma unroll
            for (int off = 32; off > 0; off >>= 1) {
                s += __shfl_xor(s, off, 64);
                c += __shfl_xor(c, off, 64);
            }
            if (lane == 0) { red_s[wv] = s; red_c[wv] = c; }
            __syncthreads();
            const float S_ = red_s[0] + red_s[1] + red_s[2] + red_s[3];
            const float C_ = red_c[0] + red_c[1] + red_c[2] + red_c[3];
            if (C_ == prevc) break;
            prevc = C_;
            tau = (S_ - 1.0f) / C_;
        }
        if (tid == 0) sh_tau = tau;
    }
    __syncthreads();
    const float tau = sh_tau;

    // bf16 output in place (all global reads completed: barriers drain vmcnt)
    short8 o;
    #pragma unroll
    for (int j = 0; j < 8; ++j) o[j] = f2bf(fmaxf(v[j] - tau, 0.f));
    *(short8*)((short*)z + tid * 8) = o;
}

extern "C" void kernel_launch(void* const* d_in, const int* in_sizes, int n_in,
                              void* d_out, int out_size, void* d_ws, size_t ws_size,
                              hipStream_t stream)
{
    (void)in_sizes; (void)n_in; (void)out_size;

    const void* queries = d_in[0];
    const void* keys    = d_in[1];
    // d_in[2] ("values") is unused by the reference.
    const void* Wq = d_in[3];
    const void* bq = d_in[4];
    const void* Wk = d_in[5];
    const void* bk = d_in[6];
    const void* Wv = d_in[7];
    const void* bv = d_in[8];
    const void* Wo = d_in[9];
    const void* bo = d_in[10];

    const int L = 2048, S = 2048, DM = 1024, H = 16, DKd = 64;
    const size_t LD = (size_t)L * DM;

    int*   flag = (int*)d_ws;
    short* Qb = (short*)((char*)d_ws + 256);
    short* Kb = Qb + LD;
    short* Vb = Kb + LD;
    short* Ob = Vb + LD;                       // [H, L, 64] bf16 contiguous
    float* Sc = (float*)(Ob + LD);             // fp32 score chunk (P bf16 written in place)

    const size_t fixedBytes = 256 + 4 * LD * sizeof(short);
    size_t remain = ws_size > fixedBytes ? ws_size - fixedBytes : 0;

    const size_t headScBytes = (size_t)L * S * sizeof(float);
    int hc = (int)(remain / headScBytes);
    int Rc;
    if (hc >= 1) { if (hc > H) hc = H; Rc = L; }
    else {
        hc = 1;
        long rows = (long)(remain / ((size_t)S * sizeof(float)));
        rows &= ~127L;
        if (rows < 128) rows = 128;
        if (rows > L) rows = L;
        Rc = (int)rows;
    }

    dim3 blk(256);

    // 0) dtype detection
    detect_k<<<dim3(1), dim3(64), 0, stream>>>((const short*)queries, 4096, flag);

    // 1) Kb = keys @ Wk + bk
    gemm_k<SRC_RT, SRC_RT, false, SRC_BF16, true><<<dim3(DM / 64, L / 64, 1), blk, 0, stream>>>(
        keys, DM, 0, Wk, DM, 0, bk, Kb, DM, 0, L, DM, DM, 1.0f, flag);
    // 2) Qb = queries @ Wq + bq
    gemm_k<SRC_RT, SRC_RT, false, SRC_BF16, true><<<dim3(DM / 64, L / 64, 1), blk, 0, stream>>>(
        queries, DM, 0, Wq, DM, 0, bq, Qb, DM, 0, L, DM, DM, 1.0f, flag);
    // 3) Vb = Kb @ Wv + bv
    gemm_k<SRC_BF16, SRC_RT, false, SRC_BF16, true><<<dim3(DM / 64, L / 64, 1), blk, 0, stream>>>(
        Kb, DM, 0, Wv, DM, 0, bv, Vb, DM, 0, S, DM, DM, 1.0f, flag);

    for (int h0 = 0; h0 < H; h0 += hc) {
        const int hn = (H - h0) < hc ? (H - h0) : hc;
        for (int r0 = 0; r0 < L; r0 += Rc) {
            const int rn = (L - r0) < Rc ? (L - r0) : Rc;
            // 4) Sc[z] = (Qb_h[r0:r0+rn] @ Kb_h^T) / 8   (128x128 tiles)
            gemm128_bt_k<<<dim3(S / 128, rn / 128, hn), blk, 0, stream>>>(
                Qb + (size_t)r0 * DM + (size_t)h0 * DKd, DM, DKd,
                Kb + (size_t)h0 * DKd, DM, DKd,
                Sc, S, (long)rn * S, DKd, 0.125f);
            // 5) sparsemax in place (fp32 in -> bf16 out at row base, lda 4096 shorts)
            sparsemax_k<<<dim3(hn * rn), blk, 0, stream>>>(Sc, S);
            // 6) Ob[h][r0:r0+rn] = P_h @ Vb_h   (A bf16 in-place P, lda=2*S shorts)
            gemm_k<SRC_BF16, SRC_BF16, false, SRC_BF16, false><<<dim3(DKd / 64, rn / 64, hn), blk, 0, stream>>>(
                (const short*)Sc, 2L * S, (long)rn * 2L * S,
                Vb + (size_t)h0 * DKd, DM, DKd,
                nullptr,
                Ob + ((size_t)h0 * L + r0) * DKd, DKd, (long)L * DKd,
                rn, DKd, S, 1.0f, flag);
        }
    }

    // 7) out = Ob(viewed [2048,1024]) @ Wo + bo -> d_out (dtype per flag)
    gemm_k<SRC_BF16, SRC_RT, false, SRC_RT, true><<<dim3(DM / 64, L / 64, 1), blk, 0, stream>>>(
        Ob, DM, 0, Wo, DM, 0, bo, d_out, DM, 0, L, DM, DM, 1.0f, flag);
}

// Round 5
// 416.398 us; speedup vs baseline: 1.5153x; 1.2095x over previous
//
#include <hip/hip_runtime.h>
#include <hip/hip_bf16.h>

// Hopfield sparsemax attention, MI355X gfx950.
// B=1, L=S=2048, D_MODEL=1024, H=16, DK=64. Inputs fp32 (runtime-detected), output per flag.
//
// Round-5 structure: everything is bf16 A [M,K] x bf16 Bt [N,K] MFMA GEMM.
//   0.  detect dtype -> flag
//   p1. Qc/Kc = bf16(queries/keys)                 [2048,1024] each
//   p2. WqT/WkT/WvT/WoT = bf16(W^T)                [1024,1024] each (LDS-tiled transpose)
//   1.  Kb = Kc @ WkT + bk                         [2048,1024] (128-tile)
//   2.  Qb = Qc @ WqT + bq                         [2048,1024] (128-tile)
//   3.  Vb = Kb @ WvT + bv                         [2048,1024] (128-tile)  (ref quirk: V from K-proj)
//   p3. Vt = Vb^T                                  [1024,2048]  -> per-head [64][2048]
//   4.  Sc = (Qb_h @ Kb_h^T)/8                     fp32 [hn,rn,S] (128-tile)
//   5.  sparsemax rows (max-pruned Michelot), writes P bf16 IN PLACE over fp32 rows
//   6.  Ob[h][l][d] = P_h @ Vt_h^T                 [H,2048,64] bf16 (64-tile, B_TRANS)
//       contiguous == reference's transpose(2,1).view(L,-1) scramble
//   7.  out = Ob @ WoT + bo -> d_out (dtype per flag, 128-tile)

typedef __attribute__((ext_vector_type(8))) short short8;
typedef __attribute__((ext_vector_type(4))) float floatx4;

#define SRC_BF16 0
#define SRC_F32  1
#define SRC_RT   2

__device__ __forceinline__ short f2bf(float f) {
    __hip_bfloat16 h = __float2bfloat16(f);
    return *reinterpret_cast<const short*>(&h);
}

// Detect input dtype: decode first n shorts as bf16; fp32-read-as-bf16 almost surely
// yields |x|>1e10 / inf / NaN. One 64-thread block.
__global__ void detect_k(const short* __restrict__ q, int n, int* __restrict__ flag)
{
    const int tid = threadIdx.x;
    int bad = 0;
    for (int i = tid; i < n; i += 64) {
        unsigned u = ((unsigned)(unsigned short)q[i]) << 16;
        float f = __uint_as_float(u);
        if (!(fabsf(f) < 1e10f)) bad = 1;
    }
    unsigned long long m = __ballot(bad != 0);
    if (tid == 0) *flag = (m != 0ULL) ? 1 : 0;
}

// Flat convert (fp32|bf16 per flag) -> bf16. z selects one of two sources. 8 elems/thread.
__global__ __launch_bounds__(256)
void convert2_k(const void* __restrict__ s0, const void* __restrict__ s1,
                short* __restrict__ d0, short* __restrict__ d1,
                const int* __restrict__ dflag)
{
    const void* s = blockIdx.z ? s1 : s0;
    short* d = blockIdx.z ? d1 : d0;
    const size_t i = ((size_t)blockIdx.x * 256 + threadIdx.x) * 8;
    short8 o;
    if (*dflag) {
        const float4 f0 = ((const float4*)((const float*)s + i))[0];
        const float4 f1 = ((const float4*)((const float*)s + i))[1];
        o[0] = f2bf(f0.x); o[1] = f2bf(f0.y); o[2] = f2bf(f0.z); o[3] = f2bf(f0.w);
        o[4] = f2bf(f1.x); o[5] = f2bf(f1.y); o[6] = f2bf(f1.z); o[7] = f2bf(f1.w);
    } else {
        o = *(const short8*)((const short*)s + i);
    }
    *(short8*)(d + i) = o;
}

// LDS-tiled transpose: src [R,C] (fp32|bf16) -> dst [C,R] bf16. 64x64 tiles, 256 threads.
// SRC: SRC_BF16 (compile-time bf16) or SRC_RT (per flag).
template<int SRC>
__global__ __launch_bounds__(256)
void transpose_k(const void* __restrict__ src, short* __restrict__ dst,
                 int R, int C, const int* __restrict__ dflag)
{
    __shared__ short T[64][72];   // 144 B row stride: 16B-aligned rows, banks spread
    const int tid = threadIdx.x;
    const int bC = blockIdx.x, bR = blockIdx.y;
    const bool f32 = (SRC == SRC_F32) || (SRC == SRC_RT && *dflag);

    const int colg = (tid & 7) * 8;
    #pragma unroll
    for (int h = 0; h < 2; ++h) {
        const int row = (tid >> 3) + 32 * h;
        const size_t idx = (size_t)(bR * 64 + row) * (size_t)C + (size_t)(bC * 64 + colg);
        short e[8];
        if (f32) {
            const float4 f0 = ((const float4*)((const float*)src + idx))[0];
            const float4 f1 = ((const float4*)((const float*)src + idx))[1];
            e[0] = f2bf(f0.x); e[1] = f2bf(f0.y); e[2] = f2bf(f0.z); e[3] = f2bf(f0.w);
            e[4] = f2bf(f1.x); e[5] = f2bf(f1.y); e[6] = f2bf(f1.z); e[7] = f2bf(f1.w);
        } else {
            short8 s = *(const short8*)((const short*)src + idx);
            #pragma unroll
            for (int j = 0; j < 8; ++j) e[j] = s[j];
        }
        #pragma unroll
        for (int j = 0; j < 8; ++j) T[colg + j][row] = e[j];
    }
    __syncthreads();
    #pragma unroll
    for (int h = 0; h < 2; ++h) {
        const int orow = (tid >> 3) + 32 * h;
        const int ocolg = (tid & 7) * 8;
        const size_t idx = (size_t)(bC * 64 + orow) * (size_t)R + (size_t)(bR * 64 + ocolg);
        *(short8*)(dst + idx) = *(const short8*)&T[orow][ocolg];
    }
}

// Batched weight transpose: 4 matrices selected by blockIdx.z.
struct TP4 {
    const void* s[4];
    short* d[4];
};
__global__ __launch_bounds__(256)
void transpose4_k(TP4 p, int R, int C, const int* __restrict__ dflag)
{
    __shared__ short T[64][72];
    const int tid = threadIdx.x;
    const int bC = blockIdx.x, bR = blockIdx.y;
    const void* src = p.s[blockIdx.z];
    short* dst = p.d[blockIdx.z];
    const bool f32 = (*dflag != 0);

    const int colg = (tid & 7) * 8;
    #pragma unroll
    for (int h = 0; h < 2; ++h) {
        const int row = (tid >> 3) + 32 * h;
        const size_t idx = (size_t)(bR * 64 + row) * (size_t)C + (size_t)(bC * 64 + colg);
        short e[8];
        if (f32) {
            const float4 f0 = ((const float4*)((const float*)src + idx))[0];
            const float4 f1 = ((const float4*)((const float*)src + idx))[1];
            e[0] = f2bf(f0.x); e[1] = f2bf(f0.y); e[2] = f2bf(f0.z); e[3] = f2bf(f0.w);
            e[4] = f2bf(f1.x); e[5] = f2bf(f1.y); e[6] = f2bf(f1.z); e[7] = f2bf(f1.w);
        } else {
            short8 s = *(const short8*)((const short*)src + idx);
            #pragma unroll
            for (int j = 0; j < 8; ++j) e[j] = s[j];
        }
        #pragma unroll
        for (int j = 0; j < 8; ++j) T[colg + j][row] = e[j];
    }
    __syncthreads();
    #pragma unroll
    for (int h = 0; h < 2; ++h) {
        const int orow = (tid >> 3) + 32 * h;
        const int ocolg = (tid & 7) * 8;
        const size_t idx = (size_t)(bC * 64 + orow) * (size_t)R + (size_t)(bR * 64 + ocolg);
        *(short8*)(dst + idx) = *(const short8*)&T[orow][ocolg];
    }
}

// ---------------- 128x128-tile GEMM: bf16 A [M,K] x bf16 Bt [N,K] ----------------
// C = alpha*A@Bt^T (+ bias). 4 waves 2x2, each wave 64x64 = 4x4 mfma_f32_16x16x32_bf16.
// BK=32. OSRC: 0=bf16, 1=f32, 2=runtime(flag). Bias dtype per flag.
template<int OSRC, bool HAS_BIAS>
__global__ __launch_bounds__(256)
void gemm128_bt_k(const short* __restrict__ Ap, long lda, long sA,
                  const short* __restrict__ Bp, long ldb, long sB,
                  const void* __restrict__ bias,
                  void* __restrict__ Cp, long ldc, long sC,
                  int K, float alpha, const int* __restrict__ dflag)
{
    __shared__ __align__(16) short As[128][40];
    __shared__ __align__(16) short Bs[128][40];

    int rtf = 0;
    if (OSRC == SRC_RT || HAS_BIAS) rtf = *dflag;

    const int tid  = threadIdx.x;
    const int bN   = blockIdx.x, bM = blockIdx.y, bz = blockIdx.z;
    const int lane = tid & 63, wave = tid >> 6;
    const int wm   = (wave >> 1) * 64;
    const int wn   = (wave & 1) * 64;
    const int quad = lane >> 4, r16 = lane & 15;

    floatx4 acc[4][4];
    #pragma unroll
    for (int i = 0; i < 4; ++i)
        #pragma unroll
        for (int j = 0; j < 4; ++j)
            acc[i][j] = (floatx4){0.f, 0.f, 0.f, 0.f};

    const int ar = tid >> 2, ac = (tid & 3) * 8;
    const short* Abase = Ap + (size_t)bz * (size_t)sA;
    const short* Bbase = Bp + (size_t)bz * (size_t)sB;

    for (int k0 = 0; k0 < K; k0 += 32) {
        #pragma unroll
        for (int c = 0; c < 2; ++c) {
            const int row = c * 64 + ar;
            *(short8*)&As[row][ac] =
                *(const short8*)(Abase + (size_t)(bM * 128 + row) * (size_t)lda + (size_t)(k0 + ac));
            *(short8*)&Bs[row][ac] =
                *(const short8*)(Bbase + (size_t)(bN * 128 + row) * (size_t)ldb + (size_t)(k0 + ac));
        }
        __syncthreads();

        short8 af[4], bfr[4];
        #pragma unroll
        for (int i = 0; i < 4; ++i) af[i]  = *(const short8*)&As[wm + i * 16 + r16][quad * 8];
        #pragma unroll
        for (int j = 0; j < 4; ++j) bfr[j] = *(const short8*)&Bs[wn + j * 16 + r16][quad * 8];
        #pragma unroll
        for (int i = 0; i < 4; ++i)
            #pragma unroll
            for (int j = 0; j < 4; ++j)
                acc[i][j] = __builtin_amdgcn_mfma_f32_16x16x32_bf16(af[i], bfr[j], acc[i][j], 0, 0, 0);
        __syncthreads();
    }

    const size_t cOff = (size_t)bz * (size_t)sC;
    const bool of32 = (OSRC == SRC_F32) || (OSRC == SRC_RT && rtf);
    #pragma unroll
    for (int j = 0; j < 4; ++j) {
        const int gc = bN * 128 + wn + j * 16 + r16;
        float bb = 0.0f;
        if (HAS_BIAS)
            bb = rtf ? ((const float*)bias)[gc]
                     : __bfloat162float(((const __hip_bfloat16*)bias)[gc]);
        #pragma unroll
        for (int i = 0; i < 4; ++i) {
            #pragma unroll
            for (int rg = 0; rg < 4; ++rg) {
                const int gr = bM * 128 + wm + i * 16 + quad * 4 + rg;
                float v = acc[i][j][rg] * alpha + bb;
                if (of32)
                    ((float*)Cp)[cOff + (size_t)gr * (size_t)ldc + gc] = v;
                else
                    ((__hip_bfloat16*)Cp)[cOff + (size_t)gr * (size_t)ldc + gc] = __float2bfloat16(v);
            }
        }
    }
}

// ---------------- 64x64-tile GEMM, bf16 A [M,K] x bf16 Bt [N,K] -> bf16 C (AV) -------
__global__ __launch_bounds__(256)
void gemm64_bt_k(const short* __restrict__ Ap, long lda, long sA,
                 const short* __restrict__ Bp, long ldb, long sB,
                 short* __restrict__ Cp, long ldc, long sC,
                 int K)
{
    __shared__ __align__(16) short As[64][40];
    __shared__ __align__(16) short Bs[64][40];

    const int tid  = threadIdx.x;
    const int bN   = blockIdx.x, bM = blockIdx.y, bz = blockIdx.z;
    const int lane = tid & 63, wave = tid >> 6;
    const int wm   = (wave >> 1) * 32;
    const int wn   = (wave & 1) * 32;
    const int quad = lane >> 4, r16 = lane & 15;

    floatx4 acc[2][2];
    #pragma unroll
    for (int i = 0; i < 2; ++i)
        #pragma unroll
        for (int j = 0; j < 2; ++j)
            acc[i][j] = (floatx4){0.f, 0.f, 0.f, 0.f};

    const int ar = tid >> 2, ac = (tid & 3) * 8;
    const short* Abase = Ap + (size_t)bz * (size_t)sA;
    const short* Bbase = Bp + (size_t)bz * (size_t)sB;

    for (int k0 = 0; k0 < K; k0 += 32) {
        *(short8*)&As[ar][ac] =
            *(const short8*)(Abase + (size_t)(bM * 64 + ar) * (size_t)lda + (size_t)(k0 + ac));
        *(short8*)&Bs[ar][ac] =
            *(const short8*)(Bbase + (size_t)(bN * 64 + ar) * (size_t)ldb + (size_t)(k0 + ac));
        __syncthreads();

        short8 a0 = *(const short8*)&As[wm + r16][quad * 8];
        short8 a1 = *(const short8*)&As[wm + 16 + r16][quad * 8];
        short8 b0 = *(const short8*)&Bs[wn + r16][quad * 8];
        short8 b1 = *(const short8*)&Bs[wn + 16 + r16][quad * 8];

        acc[0][0] = __builtin_amdgcn_mfma_f32_16x16x32_bf16(a0, b0, acc[0][0], 0, 0, 0);
        acc[0][1] = __builtin_amdgcn_mfma_f32_16x16x32_bf16(a0, b1, acc[0][1], 0, 0, 0);
        acc[1][0] = __builtin_amdgcn_mfma_f32_16x16x32_bf16(a1, b0, acc[1][0], 0, 0, 0);
        acc[1][1] = __builtin_amdgcn_mfma_f32_16x16x32_bf16(a1, b1, acc[1][1], 0, 0, 0);
        __syncthreads();
    }

    const size_t cOff = (size_t)bz * (size_t)sC;
    #pragma unroll
    for (int i = 0; i < 2; ++i)
        #pragma unroll
        for (int j = 0; j < 2; ++j) {
            const int gc = bN * 64 + wn + j * 16 + r16;
            #pragma unroll
            for (int rg = 0; rg < 4; ++rg) {
                const int gr = bM * 64 + wm + i * 16 + quad * 4 + rg;
                Cp[cOff + (size_t)gr * (size_t)ldc + gc] = f2bf(acc[i][j][rg]);
            }
        }
}

// ---------------- sparsemax: max-pruned Michelot, bf16 in-place output ----------------
// One 256-thread block per row of S=2048. Support subset of {z >= M-1}. Candidates
// compacted to LDS (typ. < 50); wave 0 solves with shuffle-only reductions. Block-wide
// fallback if > 512 candidates. Output written bf16[2048] in place at the row base.
__global__ __launch_bounds__(256)
void sparsemax_k(float* __restrict__ sc, int S)
{
    float* z = sc + (size_t)blockIdx.x * (size_t)S;
    const int tid = threadIdx.x;
    const int lane = tid & 63, wv = tid >> 6;

    float v[8];
    {
        const float4 f0 = *(const float4*)(z + tid * 8);
        const float4 f1 = *(const float4*)(z + tid * 8 + 4);
        v[0] = f0.x; v[1] = f0.y; v[2] = f0.z; v[3] = f0.w;
        v[4] = f1.x; v[5] = f1.y; v[6] = f1.z; v[7] = f1.w;
    }

    __shared__ float red_s[4], red_c[4], red_m[4];
    __shared__ float sh_tau;
    __shared__ int   sh_cnt;
    __shared__ float cand[512];

    float m = v[0];
    #pragma unroll
    for (int j = 1; j < 8; ++j) m = fmaxf(m, v[j]);
    #pragma unroll
    for (int off = 32; off > 0; off >>= 1) m = fmaxf(m, __shfl_xor(m, off, 64));
    if (lane == 0) red_m[wv] = m;
    if (tid == 0) sh_cnt = 0;
    __syncthreads();
    const float M = fmaxf(fmaxf(red_m[0], red_m[1]), fmaxf(red_m[2], red_m[3]));
    const float thr = M - 1.0f;

    #pragma unroll
    for (int j = 0; j < 8; ++j) {
        if (v[j] >= thr) {
            int p = atomicAdd(&sh_cnt, 1);
            if (p < 512) cand[p] = v[j];
        }
    }
    __syncthreads();
    const int n = sh_cnt;

    if (n <= 512) {
        if (wv == 0) {
            float c0[8];
            #pragma unroll
            for (int i = 0; i < 8; ++i) {
                const int idx = lane + i * 64;
                c0[i] = (idx < n) ? cand[idx] : -3.0e38f;
            }
            float tau = -3.0e38f, prevc = -1.0f;
            for (int it = 0; it < 64; ++it) {
                float s = 0.f, c = 0.f;
                #pragma unroll
                for (int i = 0; i < 8; ++i)
                    if (c0[i] > tau) { s += c0[i]; c += 1.f; }
                #pragma unroll
                for (int off = 32; off > 0; off >>= 1) {
                    s += __shfl_xor(s, off, 64);
                    c += __shfl_xor(c, off, 64);
                }
                if (c == prevc) break;
                prevc = c;
                tau = (s - 1.0f) / c;
            }
            if (lane == 0) sh_tau = tau;
        }
    } else {
        float ls = 0.f;
        #pragma unroll
        for (int j = 0; j < 8; ++j) ls += v[j];
        #pragma unroll
        for (int off = 32; off > 0; off >>= 1) ls += __shfl_xor(ls, off, 64);
        if (lane == 0) red_s[wv] = ls;
        __syncthreads();
        float tau = (red_s[0] + red_s[1] + red_s[2] + red_s[3] - 1.0f) / (float)S;
        float prevc = (float)S;
        for (int it = 0; it < 64; ++it) {
            __syncthreads();
            float s = 0.f, c = 0.f;
            #pragma unroll
            for (int j = 0; j < 8; ++j)
                if (v[j] > tau) { s += v[j]; c += 1.f; }
            #pragma unroll
            for (int off = 32; off > 0; off >>= 1) {
                s += __shfl_xor(s, off, 64);
                c += __shfl_xor(c, off, 64);
            }
            if (lane == 0) { red_s[wv] = s; red_c[wv] = c; }
            __syncthreads();
            const float S_ = red_s[0] + red_s[1] + red_s[2] + red_s[3];
            const float C_ = red_c[0] + red_c[1] + red_c[2] + red_c[3];
            if (C_ == prevc) break;
            prevc = C_;
            tau = (S_ - 1.0f) / C_;
        }
        if (tid == 0) sh_tau = tau;
    }
    __syncthreads();
    const float tau = sh_tau;

    short8 o;
    #pragma unroll
    for (int j = 0; j < 8; ++j) o[j] = f2bf(fmaxf(v[j] - tau, 0.f));
    *(short8*)((short*)z + tid * 8) = o;
}

extern "C" void kernel_launch(void* const* d_in, const int* in_sizes, int n_in,
                              void* d_out, int out_size, void* d_ws, size_t ws_size,
                              hipStream_t stream)
{
    (void)in_sizes; (void)n_in; (void)out_size;

    const void* queries = d_in[0];
    const void* keys    = d_in[1];
    // d_in[2] ("values") unused by the reference.
    const void* Wq = d_in[3];
    const void* bq = d_in[4];
    const void* Wk = d_in[5];
    const void* bk = d_in[6];
    const void* Wv = d_in[7];
    const void* bv = d_in[8];
    const void* Wo = d_in[9];
    const void* bo = d_in[10];

    const int L = 2048, S = 2048, DM = 1024, H = 16, DKd = 64;
    const size_t LD = (size_t)L * DM;   // 2M elements

    int*   flag = (int*)d_ws;
    short* Qc  = (short*)((char*)d_ws + 256);  // bf16 queries      [2048,1024]
    short* Kc  = Qc + LD;                      // bf16 keys         [2048,1024]
    short* WqT = Kc + LD;                      // bf16 Wq^T         [1024,1024]
    short* WkT = WqT + (size_t)DM * DM;
    short* WvT = WkT + (size_t)DM * DM;
    short* WoT = WvT + (size_t)DM * DM;
    short* Qb  = WoT + (size_t)DM * DM;        // [2048,1024]
    short* Kb  = Qb + LD;
    short* Vb  = Kb + LD;
    short* Vt  = Vb + LD;                      // [1024,2048] = per-head [64][2048]
    short* Ob  = Vt + LD;                      // [H,2048,64] contiguous
    float* Sc  = (float*)(Ob + LD);            // fp32 score chunk (P bf16 in place)

    const size_t fixedBytes = 256 + (9 * LD + 4 * (size_t)DM * DM) * sizeof(short); // ~44 MB
    size_t remain = ws_size > fixedBytes ? ws_size - fixedBytes : 0;

    const size_t headScBytes = (size_t)L * S * sizeof(float);  // 16 MB
    int hc = (int)(remain / headScBytes);
    int Rc;
    if (hc >= 1) { if (hc > H) hc = H; Rc = L; }
    else {
        hc = 1;
        long rows = (long)(remain / ((size_t)S * sizeof(float)));
        rows &= ~127L;
        if (rows < 128) rows = 128;
        if (rows > L) rows = L;
        Rc = (int)rows;
    }

    dim3 blk(256);

    // 0) dtype detection
    detect_k<<<dim3(1), dim3(64), 0, stream>>>((const short*)queries, 4096, flag);

    // p1) convert queries/keys -> bf16
    convert2_k<<<dim3((unsigned)(LD / 2048), 1, 2), blk, 0, stream>>>(
        queries, keys, Qc, Kc, flag);

    // p2) transpose-convert the 4 weight matrices -> bf16 [N][K]
    {
        TP4 p;
        p.s[0] = Wq; p.s[1] = Wk; p.s[2] = Wv; p.s[3] = Wo;
        p.d[0] = WqT; p.d[1] = WkT; p.d[2] = WvT; p.d[3] = WoT;
        transpose4_k<<<dim3(DM / 64, DM / 64, 4), blk, 0, stream>>>(p, DM, DM, flag);
    }

    // 1) Kb = Kc @ WkT + bk
    gemm128_bt_k<SRC_BF16, true><<<dim3(DM / 128, L / 128, 1), blk, 0, stream>>>(
        Kc, DM, 0, WkT, DM, 0, bk, Kb, DM, 0, DM, 1.0f, flag);
    // 2) Qb = Qc @ WqT + bq
    gemm128_bt_k<SRC_BF16, true><<<dim3(DM / 128, L / 128, 1), blk, 0, stream>>>(
        Qc, DM, 0, WqT, DM, 0, bq, Qb, DM, 0, DM, 1.0f, flag);
    // 3) Vb = Kb @ WvT + bv
    gemm128_bt_k<SRC_BF16, true><<<dim3(DM / 128, L / 128, 1), blk, 0, stream>>>(
        Kb, DM, 0, WvT, DM, 0, bv, Vb, DM, 0, DM, 1.0f, flag);
    // p3) Vt = Vb^T  ([2048,1024] -> [1024,2048])
    transpose_k<SRC_BF16><<<dim3(DM / 64, L / 64, 1), blk, 0, stream>>>(
        Vb, Vt, L, DM, flag);

    for (int h0 = 0; h0 < H; h0 += hc) {
        const int hn = (H - h0) < hc ? (H - h0) : hc;
        for (int r0 = 0; r0 < L; r0 += Rc) {
            const int rn = (L - r0) < Rc ? (L - r0) : Rc;
            // 4) Sc[z] = (Qb_h[r0:r0+rn] @ Kb_h^T) / 8
            gemm128_bt_k<SRC_F32, false><<<dim3(S / 128, rn / 128, hn), blk, 0, stream>>>(
                Qb + (size_t)r0 * DM + (size_t)h0 * DKd, DM, DKd,
                Kb + (size_t)h0 * DKd, DM, DKd,
                nullptr,
                Sc, S, (long)rn * S, DKd, 0.125f, flag);
            // 5) sparsemax in place (fp32 in -> bf16 out at row base)
            sparsemax_k<<<dim3(hn * rn), blk, 0, stream>>>(Sc, S);
            // 6) Ob[h][r0:r0+rn] = P_h @ Vt_h^T  (A: bf16 in-place P, lda=2S shorts)
            gemm64_bt_k<<<dim3(DKd / 64, rn / 64, hn), blk, 0, stream>>>(
                (const short*)Sc, 2L * S, (long)rn * 2L * S,
                Vt + (size_t)h0 * DKd * S, S, (long)DKd * S,
                Ob + ((size_t)h0 * L + r0) * DKd, DKd, (long)L * DKd,
                S);
        }
    }

    // 7) out = Ob(viewed [2048,1024]) @ WoT + bo -> d_out (dtype per flag)
    gemm128_bt_k<SRC_RT, true><<<dim3(DM / 128, L / 128, 1), blk, 0, stream>>>(
        Ob, DM, 0, WoT, DM, 0, bo, d_out, DM, 0, DM, 1.0f, flag);
}